// Round 1
// baseline (11.325 us; speedup 1.0000x reference)
//
#include <hip/hip_runtime.h>
#include <hip/hip_bf16.h>

// Output layout: out[0..6143] = bond_lens (2,4,768) row-major,
//                out[6144..6147] = max_bond_dev_per_replica (4,)

__device__ __forceinline__ float axis_min_sq(float ci, float cj, float box) {
    // min over shift s in {-box, 0, +box} of (ci - (cj + s))^2
    float d0 = ci - (cj - box);
    float d1 = ci - cj;
    float d2 = ci - (cj + box);
    d0 *= d0; d1 *= d1; d2 *= d2;
    return fminf(d0, fminf(d1, d2));
}

__global__ __launch_bounds__(256) void bond_dev_kernel(
    const float* __restrict__ radii,   // (2,4,512,3)
    const float* __restrict__ cell,    // (3,3) diagonal
    const int*   __restrict__ bonds,   // (768,2)
    const float* __restrict__ mean,    // (768,)
    float*       __restrict__ out)     // 6144 + 4
{
    const int idx = blockIdx.x * 256 + threadIdx.x;   // 0..6143
    const int b = idx % 768;
    const int s = (idx / 768) & 3;
    const int r = idx / 3072;

    const float bx = cell[0];
    const float by = cell[4];
    const float bz = cell[8];

    const int i = bonds[2 * b];
    const int j = bonds[2 * b + 1];

    const float* base = radii + (size_t)((r * 4 + s) * 512) * 3;
    const float xi = base[3 * i], yi = base[3 * i + 1], zi = base[3 * i + 2];
    const float xj = base[3 * j], yj = base[3 * j + 1], zj = base[3 * j + 2];

    const float dsq = axis_min_sq(xi, xj, bx)
                    + axis_min_sq(yi, yj, by)
                    + axis_min_sq(zi, zj, bz);
    const float len = sqrtf(dsq);
    out[idx] = len;

    // dev >= 0 always
    float v = fabsf(len - mean[b]);

    // wave-64 reduce max
    #pragma unroll
    for (int o = 32; o > 0; o >>= 1)
        v = fmaxf(v, __shfl_down(v, o, 64));

    __shared__ float wmax[4];
    const int lane = threadIdx.x & 63;
    const int wid  = threadIdx.x >> 6;
    if (lane == 0) wmax[wid] = v;
    __syncthreads();

    if (threadIdx.x == 0) {
        const float m = fmaxf(fmaxf(wmax[0], wmax[1]), fmaxf(wmax[2], wmax[3]));
        // all values nonnegative -> uint ordering == float ordering
        atomicMax((unsigned int*)(out + 6144 + s), __float_as_uint(m));
    }
}

extern "C" void kernel_launch(void* const* d_in, const int* in_sizes, int n_in,
                              void* d_out, int out_size, void* d_ws, size_t ws_size,
                              hipStream_t stream) {
    const float* radii = (const float*)d_in[0];   // (2,4,512,3)
    const float* cell  = (const float*)d_in[1];   // (3,3)
    const int*   bonds = (const int*)d_in[2];     // (768,2)
    const float* mean  = (const float*)d_in[3];   // (768,)
    float* out = (float*)d_out;

    // init the 4 max-dev accumulators to 0 (devs are >= 0)
    hipMemsetAsync((char*)d_out + 6144 * sizeof(float), 0, 4 * sizeof(float), stream);

    const int total = 2 * 4 * 768;                // 6144
    bond_dev_kernel<<<total / 256, 256, 0, stream>>>(radii, cell, bonds, mean, out);
}

// Round 2
// 9.660 us; speedup vs baseline: 1.1724x; 1.1724x over previous
//
#include <hip/hip_runtime.h>
#include <hip/hip_bf16.h>

// Output layout: out[0..6143] = bond_lens (2,4,768) row-major,
//                out[6144..6147] = max_bond_dev_per_replica (4,)
//
// Diagonal cell (box * I): min over the 27 lattice-shift images factorizes
// per-axis: min_{s in 27} sum_a (d_a - s_a)^2 = sum_a min_{s in {-L,0,L}} (d_a - s)^2.
// Exact (term-wise monotone), matches the reference's min-of-27.

__device__ __forceinline__ float axis_min_sq(float ci, float cj, float box) {
    float d0 = ci - (cj - box);
    float d1 = ci - cj;
    float d2 = ci - (cj + box);
    d0 *= d0; d1 *= d1; d2 *= d2;
    return fminf(d0, fminf(d1, d2));
}

// grid = 4 (one block per system s), block = 256.
// Each thread handles bonds {t, t+256, t+512} for both replicas -> 6 dists.
__global__ __launch_bounds__(256) void bond_dev_kernel(
    const float* __restrict__ radii,   // (2,4,512,3)
    const float* __restrict__ cell,    // (3,3) diagonal
    const int*   __restrict__ bonds,   // (768,2)
    const float* __restrict__ mean,    // (768,)
    float*       __restrict__ out)     // 6144 + 4
{
    const int s = blockIdx.x;
    const int t = threadIdx.x;

    const float bx = cell[0];
    const float by = cell[4];
    const float bz = cell[8];

    float vmax = 0.0f;

    #pragma unroll
    for (int k = 0; k < 3; ++k) {
        const int b = k * 256 + t;
        const int i = bonds[2 * b];
        const int j = bonds[2 * b + 1];
        const float mb = mean[b];

        #pragma unroll
        for (int r = 0; r < 2; ++r) {
            const float* base = radii + (size_t)((r * 4 + s) * 512) * 3;
            const float xi = base[3 * i], yi = base[3 * i + 1], zi = base[3 * i + 2];
            const float xj = base[3 * j], yj = base[3 * j + 1], zj = base[3 * j + 2];

            const float dsq = axis_min_sq(xi, xj, bx)
                            + axis_min_sq(yi, yj, by)
                            + axis_min_sq(zi, zj, bz);
            const float len = sqrtf(dsq);
            out[(r * 4 + s) * 768 + b] = len;
            vmax = fmaxf(vmax, fabsf(len - mb));
        }
    }

    // block-wide max reduction (4 waves of 64)
    #pragma unroll
    for (int o = 32; o > 0; o >>= 1)
        vmax = fmaxf(vmax, __shfl_down(vmax, o, 64));

    __shared__ float wmax[4];
    const int lane = t & 63;
    const int wid  = t >> 6;
    if (lane == 0) wmax[wid] = vmax;
    __syncthreads();

    if (t == 0)
        out[6144 + s] = fmaxf(fmaxf(wmax[0], wmax[1]), fmaxf(wmax[2], wmax[3]));
}

extern "C" void kernel_launch(void* const* d_in, const int* in_sizes, int n_in,
                              void* d_out, int out_size, void* d_ws, size_t ws_size,
                              hipStream_t stream) {
    const float* radii = (const float*)d_in[0];   // (2,4,512,3)
    const float* cell  = (const float*)d_in[1];   // (3,3)
    const int*   bonds = (const int*)d_in[2];     // (768,2)
    const float* mean  = (const float*)d_in[3];   // (768,)
    float* out = (float*)d_out;

    bond_dev_kernel<<<4, 256, 0, stream>>>(radii, cell, bonds, mean, out);
}

// Round 3
// 9.343 us; speedup vs baseline: 1.2121x; 1.0339x over previous
//
#include <hip/hip_runtime.h>
#include <hip/hip_bf16.h>

// Output layout: out[0..6143] = bond_lens (2,4,768) row-major,
//                out[6144..6147] = max_bond_dev_per_replica (4,)
//
// Diagonal cell (box * I): min over the 27 lattice-shift images factorizes
// per-axis: min_{s in 27} sum_a (d_a - s_a)^2 = sum_a min_{s in {-L,0,L}} (d_a - s)^2.
// Exact (term-wise monotone), matches the reference's min-of-27.

__device__ __forceinline__ float axis_min_sq(float ci, float cj, float box) {
    float d0 = ci - (cj - box);
    float d1 = ci - cj;
    float d2 = ci - (cj + box);
    d0 *= d0; d1 *= d1; d2 *= d2;
    return fminf(d0, fminf(d1, d2));
}

// grid = 4 (one block per system s), block = 768 (one bond per thread).
// Each thread: 1 index load -> 4 independent coordinate gathers (2 atoms x 2
// replicas) -> 2 coalesced stores. Shortest possible dependent-miss chain.
__global__ __launch_bounds__(768) void bond_dev_kernel(
    const float* __restrict__ radii,   // (2,4,512,3)
    const float* __restrict__ cell,    // (3,3) diagonal
    const int*   __restrict__ bonds,   // (768,2)
    const float* __restrict__ mean,    // (768,)
    float*       __restrict__ out)     // 6144 + 4
{
    const int s = blockIdx.x;
    const int b = threadIdx.x;         // 0..767

    const float bx = cell[0];
    const float by = cell[4];
    const float bz = cell[8];

    const int i = bonds[2 * b];
    const int j = bonds[2 * b + 1];
    const float mb = mean[b];

    float vmax = 0.0f;

    #pragma unroll
    for (int r = 0; r < 2; ++r) {
        const float* base = radii + (size_t)((r * 4 + s) * 512) * 3;
        const float xi = base[3 * i], yi = base[3 * i + 1], zi = base[3 * i + 2];
        const float xj = base[3 * j], yj = base[3 * j + 1], zj = base[3 * j + 2];

        const float dsq = axis_min_sq(xi, xj, bx)
                        + axis_min_sq(yi, yj, by)
                        + axis_min_sq(zi, zj, bz);
        const float len = sqrtf(dsq);
        out[(r * 4 + s) * 768 + b] = len;
        vmax = fmaxf(vmax, fabsf(len - mb));
    }

    // block-wide max reduction: wave-64 shuffle, then 12 wave leaders via LDS
    #pragma unroll
    for (int o = 32; o > 0; o >>= 1)
        vmax = fmaxf(vmax, __shfl_down(vmax, o, 64));

    __shared__ float wmax[12];
    const int lane = b & 63;
    const int wid  = b >> 6;
    if (lane == 0) wmax[wid] = vmax;
    __syncthreads();

    if (b == 0) {
        float m = wmax[0];
        #pragma unroll
        for (int w = 1; w < 12; ++w) m = fmaxf(m, wmax[w]);
        out[6144 + s] = m;
    }
}

extern "C" void kernel_launch(void* const* d_in, const int* in_sizes, int n_in,
                              void* d_out, int out_size, void* d_ws, size_t ws_size,
                              hipStream_t stream) {
    const float* radii = (const float*)d_in[0];   // (2,4,512,3)
    const float* cell  = (const float*)d_in[1];   // (3,3)
    const int*   bonds = (const int*)d_in[2];     // (768,2)
    const float* mean  = (const float*)d_in[3];   // (768,)
    float* out = (float*)d_out;

    bond_dev_kernel<<<4, 768, 0, stream>>>(radii, cell, bonds, mean, out);
}